// Round 7
// baseline (170.834 us; speedup 1.0000x reference)
//
#include <hip/hip_runtime.h>
#include <hip/hip_fp16.h>
#include <math.h>

// Capsule routing, fused, register-resident, fp16-staged, d-split, softmax
// WITHOUT max-subtraction (|b| <~ 1, exp safe in fp32 -> softmax exact).
// 640 threads/block: thread = (j = wave 0..9, dhalf = bit5, ns = lane&31).
// Per iteration, ONE barrier region: [B (read e,sacc -> t) ; C (shfl-reduce
// -> s, squash) ; D (u = v·W -> ua registers) ; E (e = exp(ua·(x,1)) -> LDS,
// atomicAdd denominator sacc_next)].  b / pred / Ul never materialized.
// LDS: xs row-major fp16 (1 ds_read_b128 per (p, fragment)), e2 (fp16 pairs),
// sacc double-buffered (zeroed once at staging).
// NOTE: __launch_bounds__ 2nd arg >=5 clamps VGPR to 48 (R4/R5 spill
// cascades). Keep 2; compiler lands ~80-90 VGPR -> 5 waves/EU.

#define BSZ   512
#define C_IN  256
#define HW    36
#define NS    32
#define NOC   10
#define OD    16
#define ROUTE 3
#define NIC   1152
#define NT    640

__device__ __forceinline__ float fast_rcp(float v) {
#if defined(__has_builtin)
#if __has_builtin(__builtin_amdgcn_rcpf)
    return __builtin_amdgcn_rcpf(v);
#else
    return 1.0f / v;
#endif
#else
    return 1.0f / v;
#endif
}

__global__ __launch_bounds__(256) void convert_w(
    const float* __restrict__ Wc, const float* __restrict__ bc,
    __half* __restrict__ w16)   // [40960 W | 5120 bias]
{
    const int n = 40960 + 5120;
    for (int i = blockIdx.x * 256 + threadIdx.x; i < n; i += gridDim.x * 256) {
        float v = (i < 40960) ? Wc[i] : bc[i - 40960];
        w16[i] = __float2half(v);
    }
}

__global__ __launch_bounds__(NT, 2) void caps_kernel(
    const float*  __restrict__ x,     // [BSZ, 256, 36] fp32
    const __half* __restrict__ w16,   // [5120, 8] fp16
    const __half* __restrict__ bc16,  // [5120] fp16
    float* __restrict__ out)          // [BSZ, 10, 16] fp32
{
    __shared__ __half2 xs[NIC * 4];        // 18432 B: row p*32+ns, 8 halfs -> b128
    __shared__ float   sacc[2 * NIC];      //  9216 B: denom, idx (p>>1)*64+ns*2+(p&1)
    __shared__ __half2 e2[NOC * 18 * 32];  // 23040 B: exp(b) pairs, (j*18+pr)*32+ns
    // total 50688 B -> 2 blocks/CU LDS-wise

    const int tid = threadIdx.x;
    const float* xb = x + (size_t)blockIdx.x * (C_IN * HW);

    // ---- Stage x -> fp16 LDS, row-major. task = p4*128 + c2, c2 = nsc*4+k2.
    // Write bank = c2 mod 32 for consecutive lanes -> conflict-free.
    for (int t5 = tid; t5 < 9 * 128; t5 += NT) {
        int p4 = t5 >> 7, c2 = t5 & 127;
        int nsc = c2 >> 2, k2 = c2 & 3;
        const float* s0 = xb + (2 * c2) * HW + p4 * 4;
        float4 a = *(const float4*)s0;
        float4 b = *(const float4*)(s0 + HW);
        xs[((p4 * 4 + 0) * 32 + nsc) * 4 + k2] = __floats2half2_rn(a.x, b.x);
        xs[((p4 * 4 + 1) * 32 + nsc) * 4 + k2] = __floats2half2_rn(a.y, b.y);
        xs[((p4 * 4 + 2) * 32 + nsc) * 4 + k2] = __floats2half2_rn(a.z, b.z);
        xs[((p4 * 4 + 3) * 32 + nsc) * 4 + k2] = __floats2half2_rn(a.w, b.w);
    }
    for (int i5 = tid; i5 < 2 * NIC; i5 += NT) sacc[i5] = 0.f;
    __syncthreads();

    const int j     = tid >> 6;         // 0..9 (= wave index)
    const int dhalf = (tid >> 5) & 1;   // which 8 of the 16 out-dims
    const int ns    = tid & 31;

    const __half* wbase = w16 + (size_t)(ns * 160 + j * 16 + dhalf * 8) * 8;
    float bcv[8];
    {
        uint4 bv = *(const uint4*)(bc16 + ns * 160 + j * 16 + dhalf * 8);
        float2 b0 = __half22float2(*(__half2*)&bv.x);
        float2 b1 = __half22float2(*(__half2*)&bv.y);
        float2 b2 = __half22float2(*(__half2*)&bv.z);
        float2 b3 = __half22float2(*(__half2*)&bv.w);
        bcv[0]=b0.x; bcv[1]=b0.y; bcv[2]=b1.x; bcv[3]=b1.y;
        bcv[4]=b2.x; bcv[5]=b2.y; bcv[6]=b3.x; bcv[7]=b3.y;
    }

    const int q0 = dhalf * 9;   // own p-pairs pr = q0..q0+8 (p = 2*pr, 2*pr+1)
    float ua[9];                // cumulative routing coefficients (after it 0)

    for (int it = 0; it < ROUTE; ++it) {
        // ---- Phase B: t[k] = sum_p c*x[k,p] (own 18 p), merge dhalf pair ----
        float t[9];
        #pragma unroll
        for (int kk = 0; kk < 9; ++kk) t[kk] = 0.f;
        if (it == 0) {
            #pragma unroll
            for (int q = 0; q < 9; ++q) {
                int pr = q0 + q;
                #pragma unroll
                for (int s = 0; s < 2; ++s) {
                    uint4 xv = *(const uint4*)&xs[((2 * pr + s) * 32 + ns) * 4];
                    float2 f0 = __half22float2(*(__half2*)&xv.x);
                    float2 f1 = __half22float2(*(__half2*)&xv.y);
                    float2 f2 = __half22float2(*(__half2*)&xv.z);
                    float2 f3 = __half22float2(*(__half2*)&xv.w);
                    t[0] += f0.x; t[1] += f0.y; t[2] += f1.x; t[3] += f1.y;
                    t[4] += f2.x; t[5] += f2.y; t[6] += f3.x; t[7] += f3.y;
                }
            }
            #pragma unroll
            for (int kk = 0; kk < 8; ++kk) {
                t[kk] += __shfl_xor(t[kk], 32);
                t[kk] *= 0.1f;
            }
            t[8] = 3.6f;
        } else {
            const float* sb = sacc + (it - 1) * NIC;
            #pragma unroll
            for (int q = 0; q < 9; ++q) {
                int pr = q0 + q;
                float2 sv = *(const float2*)&sb[pr * 64 + ns * 2];
                float2 ev = __half22float2(e2[(j * 18 + pr) * 32 + ns]);
                float cc[2] = { ev.x * fast_rcp(sv.x), ev.y * fast_rcp(sv.y) };
                #pragma unroll
                for (int s = 0; s < 2; ++s) {
                    uint4 xv = *(const uint4*)&xs[((2 * pr + s) * 32 + ns) * 4];
                    float2 f0 = __half22float2(*(__half2*)&xv.x);
                    float2 f1 = __half22float2(*(__half2*)&xv.y);
                    float2 f2 = __half22float2(*(__half2*)&xv.z);
                    float2 f3 = __half22float2(*(__half2*)&xv.w);
                    float c = cc[s];
                    t[0] += c*f0.x; t[1] += c*f0.y; t[2] += c*f1.x; t[3] += c*f1.y;
                    t[4] += c*f2.x; t[5] += c*f2.y; t[6] += c*f3.x; t[7] += c*f3.y;
                    t[8] += c;
                }
            }
            #pragma unroll
            for (int kk = 0; kk < 9; ++kk) t[kk] += __shfl_xor(t[kk], 32);
        }

        // ---- Phase C: ps[dd] = W·t + bcv*cs (own 8 d); butterfly over ns ----
        float ps[8];
        #pragma unroll
        for (int dd = 0; dd < 8; ++dd) {
            uint4 wv = *(const uint4*)(wbase + (size_t)dd * 8);
            float2 w0 = __half22float2(*(__half2*)&wv.x);
            float2 w1 = __half22float2(*(__half2*)&wv.y);
            float2 w2 = __half22float2(*(__half2*)&wv.z);
            float2 w3 = __half22float2(*(__half2*)&wv.w);
            ps[dd] = w0.x*t[0] + w0.y*t[1] + w1.x*t[2] + w1.y*t[3]
                   + w2.x*t[4] + w2.y*t[5] + w3.x*t[6] + w3.y*t[7]
                   + bcv[dd] * t[8];
        }
        #pragma unroll
        for (int mk = 1; mk < 32; mk <<= 1) {
            #pragma unroll
            for (int dd = 0; dd < 8; ++dd)
                ps[dd] += __shfl_xor(ps[dd], mk);
        }
        float ssp = 0.f;
        #pragma unroll
        for (int dd = 0; dd < 8; ++dd) ssp += ps[dd] * ps[dd];
        float ss = ssp + __shfl_xor(ssp, 32);
        float fc = sqrtf(ss) / (1.f + ss);

        if (it == ROUTE - 1) {
            if (ns == 0) {
                float* o = out + (size_t)blockIdx.x * (NOC * OD) + j * OD + dhalf * 8;
                *(float4*)o       = make_float4(ps[0]*fc, ps[1]*fc, ps[2]*fc, ps[3]*fc);
                *(float4*)(o + 4) = make_float4(ps[4]*fc, ps[5]*fc, ps[6]*fc, ps[7]*fc);
            }
            break;
        }

        // ---- Phase D: u[k] = sum_d v[d]*W[r,k] (own 8 d); merge dhalf pair ----
        float u[9];
        #pragma unroll
        for (int kk = 0; kk < 9; ++kk) u[kk] = 0.f;
        #pragma unroll
        for (int dd = 0; dd < 8; ++dd) {
            float vv = ps[dd] * fc;
            uint4 wv = *(const uint4*)(wbase + (size_t)dd * 8);
            float2 w0 = __half22float2(*(__half2*)&wv.x);
            float2 w1 = __half22float2(*(__half2*)&wv.y);
            float2 w2 = __half22float2(*(__half2*)&wv.z);
            float2 w3 = __half22float2(*(__half2*)&wv.w);
            u[0] += vv*w0.x; u[1] += vv*w0.y; u[2] += vv*w1.x; u[3] += vv*w1.y;
            u[4] += vv*w2.x; u[5] += vv*w2.y; u[6] += vv*w3.x; u[7] += vv*w3.y;
            u[8] += vv*bcv[dd];
        }
        #pragma unroll
        for (int kk = 0; kk < 9; ++kk) u[kk] += __shfl_xor(u[kk], 32);
        if (it == 0) {
            #pragma unroll
            for (int kk = 0; kk < 9; ++kk) ua[kk] = u[kk];
        } else {
            #pragma unroll
            for (int kk = 0; kk < 9; ++kk) ua[kk] += u[kk];
        }

        // ---- Phase E: e = exp(ua·(x,1)); store fp16; atomicAdd denom ----
        {
            float* so = sacc + it * NIC;
            #pragma unroll
            for (int q = 0; q < 9; ++q) {
                int pr = q0 + q;
                float eb[2];
                #pragma unroll
                for (int s = 0; s < 2; ++s) {
                    uint4 xv = *(const uint4*)&xs[((2 * pr + s) * 32 + ns) * 4];
                    float2 f0 = __half22float2(*(__half2*)&xv.x);
                    float2 f1 = __half22float2(*(__half2*)&xv.y);
                    float2 f2 = __half22float2(*(__half2*)&xv.z);
                    float2 f3 = __half22float2(*(__half2*)&xv.w);
                    float bb = ua[8]
                        + ua[0]*f0.x + ua[1]*f0.y + ua[2]*f1.x + ua[3]*f1.y
                        + ua[4]*f2.x + ua[5]*f2.y + ua[6]*f3.x + ua[7]*f3.y;
                    eb[s] = __expf(bb);
                }
                e2[(j * 18 + pr) * 32 + ns] = __floats2half2_rn(eb[0], eb[1]);
                atomicAdd(&so[pr * 64 + ns * 2 + 0], eb[0]);
                atomicAdd(&so[pr * 64 + ns * 2 + 1], eb[1]);
            }
        }
        __syncthreads();
    }
}

extern "C" void kernel_launch(void* const* d_in, const int* in_sizes, int n_in,
                              void* d_out, int out_size, void* d_ws, size_t ws_size,
                              hipStream_t stream) {
    const float* x  = (const float*)d_in[0];
    // d_in[1] = target (int32) — unused in forward
    const float* Wc = (const float*)d_in[2];
    const float* bc = (const float*)d_in[3];
    float* out = (float*)d_out;

    __half* w16 = (__half*)d_ws;        // 40960 W halfs + 5120 bias halfs = 92160 B
    convert_w<<<dim3(48), dim3(256), 0, stream>>>(Wc, bc, w16);
    caps_kernel<<<dim3(BSZ), dim3(NT), 0, stream>>>(x, w16, w16 + 40960, out);
}

// Round 9
// 104.521 us; speedup vs baseline: 1.6344x; 1.6344x over previous
//
#include <hip/hip_runtime.h>
#include <hip/hip_fp16.h>
#include <math.h>

// Capsule routing, fused, packed-fp16 math, no atomics, no materialized b/pred.
// 640 thr/block: thread = (j = wave 0..9, dhalf = bit5, ns = lane&31).
// Per iter: B (c = exp(ua·x)*sinv, t2 += c*x, packed) -> C (ps = W·t, 5-stage
// butterfly over ns) -> D (u = v·W packed, ua += u) -> E (e = exp(ua·x) -> LDS
// fp16) -> barrier -> A' (sinv[i] = 1/sum_j e) -> barrier.
// R8 BUG FIX: iter-0 cs must be 1.8 per dhalf-half so the unconditional pair
// merge yields 3.6 (R8 had 3.6+3.6=7.2 -> doubled bias term, absmax 0.15).
// e-row layout: 12 halfs = 10 e[j] + f32 sinv in slots 10-11 (24 B rows ->
// 2-way bank aliasing = free). xs: fp16 8-half rows, ds_read_b128 (0 confl, R7).
// Softmax without max-subtraction: |b| <~ 5, exp safe (validated R7).
// __launch_bounds__(640,2): allocator targets 84 VGPR (2nd arg >=5 clamps to
// 48 VGPR -> R4/R5 spill cascade; keep 2).

#define BSZ   512
#define C_IN  256
#define HW    36
#define NS    32
#define NOC   10
#define OD    16
#define ROUTE 3
#define NIC   1152
#define NT    640
#define EROW  12

typedef __half2 h2;

__device__ __forceinline__ h2 u2h(unsigned int v) {
    union { unsigned int u; h2 h; } x; x.u = v; return x.h;
}
__device__ __forceinline__ h2 shflx_h2(h2 v, int m) {
    union { h2 h; int i; } x; x.h = v; x.i = __shfl_xor(x.i, m); return x.h;
}

__global__ __launch_bounds__(256) void convert_w(
    const float* __restrict__ Wc, const float* __restrict__ bc,
    __half* __restrict__ w16)   // [40960 W | 5120 bias]
{
    const int n = 40960 + 5120;
    for (int i = blockIdx.x * 256 + threadIdx.x; i < n; i += gridDim.x * 256) {
        float v = (i < 40960) ? Wc[i] : bc[i - 40960];
        w16[i] = __float2half(v);
    }
}

__global__ __launch_bounds__(NT, 2) void caps_kernel(
    const float*  __restrict__ x,     // [BSZ, 256, 36] fp32
    const __half* __restrict__ w16,   // [5120, 8] fp16
    const __half* __restrict__ bc16,  // [5120] fp16
    float* __restrict__ out)          // [BSZ, 10, 16] fp32
{
    __shared__ h2 xs[NIC * 4];                 // 18432 B: row i=p*32+ns, 8 halfs
    __shared__ unsigned short eL[NIC * EROW];  // 27648 B: e[j] halfs + sinv f32
    // total 46080 B -> 2 blocks/CU

    const int tid = threadIdx.x;
    const float* xb = x + (size_t)blockIdx.x * (C_IN * HW);

    // ---- Stage x -> fp16 LDS row-major (R7 layout; measured 0 conflicts) ----
    for (int t5 = tid; t5 < 9 * 128; t5 += NT) {
        int p4 = t5 >> 7, c2 = t5 & 127;
        int nsc = c2 >> 2, k2 = c2 & 3;
        const float* s0 = xb + (2 * c2) * HW + p4 * 4;
        float4 a = *(const float4*)s0;
        float4 b = *(const float4*)(s0 + HW);
        xs[((p4 * 4 + 0) * 32 + nsc) * 4 + k2] = __floats2half2_rn(a.x, b.x);
        xs[((p4 * 4 + 1) * 32 + nsc) * 4 + k2] = __floats2half2_rn(a.y, b.y);
        xs[((p4 * 4 + 2) * 32 + nsc) * 4 + k2] = __floats2half2_rn(a.z, b.z);
        xs[((p4 * 4 + 3) * 32 + nsc) * 4 + k2] = __floats2half2_rn(a.w, b.w);
    }
    __syncthreads();

    const int j     = tid >> 6;         // 0..9 (= wave index)
    const int dhalf = (tid >> 5) & 1;   // which 8 of the 16 out-dims
    const int ns    = tid & 31;

    const __half* wbase = w16 + (size_t)(ns * 160 + j * 16 + dhalf * 8) * 8;
    float bcv[8];
    {
        uint4 bv = *(const uint4*)(bc16 + ns * 160 + j * 16 + dhalf * 8);
        float2 b0 = __half22float2(u2h(bv.x));
        float2 b1 = __half22float2(u2h(bv.y));
        float2 b2 = __half22float2(u2h(bv.z));
        float2 b3 = __half22float2(u2h(bv.w));
        bcv[0]=b0.x; bcv[1]=b0.y; bcv[2]=b1.x; bcv[3]=b1.y;
        bcv[4]=b2.x; bcv[5]=b2.y; bcv[6]=b3.x; bcv[7]=b3.y;
    }

    const int q0 = dhalf * 9;   // own p-pairs pr = q0..q0+8
    float ua[9];                // cumulative routing coefficients (f32 canonical)
    h2    ua2[4];               // packed mirror for the fp16 dots

    for (int it = 0; it < ROUTE; ++it) {
        // ---- Phase B: t2[k2] = sum_p c*x2, tc = sum_p c (own 18 p) ----
        h2 t2[4];
        h2 zz = __float2half2_rn(0.f);
        t2[0] = zz; t2[1] = zz; t2[2] = zz; t2[3] = zz;
        float tc = 0.f;
        if (it == 0) {
            #pragma unroll
            for (int q = 0; q < 9; ++q) {
                #pragma unroll
                for (int s = 0; s < 2; ++s) {
                    int row = (2 * (q0 + q) + s) * 32 + ns;
                    uint4 xv = *(const uint4*)&xs[row * 4];
                    t2[0] = __hadd2(t2[0], u2h(xv.x));
                    t2[1] = __hadd2(t2[1], u2h(xv.y));
                    t2[2] = __hadd2(t2[2], u2h(xv.z));
                    t2[3] = __hadd2(t2[3], u2h(xv.w));
                }
            }
            h2 tenth = __float2half2_rn(0.1f);
            #pragma unroll
            for (int k = 0; k < 4; ++k) t2[k] = __hmul2(t2[k], tenth);
            tc = 1.8f;   // per-half; pair merge below doubles to 3.6 (= sum_p 0.1)
        } else {
            #pragma unroll
            for (int q = 0; q < 9; ++q) {
                #pragma unroll
                for (int s = 0; s < 2; ++s) {
                    int row = (2 * (q0 + q) + s) * 32 + ns;
                    uint4 xv = *(const uint4*)&xs[row * 4];
                    h2 x0 = u2h(xv.x), x1 = u2h(xv.y), x2 = u2h(xv.z), x3 = u2h(xv.w);
                    h2 a = __hmul2(ua2[0], x0);
                    a = __hfma2(ua2[1], x1, a);
                    a = __hfma2(ua2[2], x2, a);
                    a = __hfma2(ua2[3], x3, a);
                    float2 af = __half22float2(a);
                    float bb = ua[8] + af.x + af.y;
                    float sv = *(const float*)&eL[row * EROW + 10];
                    float c = __expf(bb) * sv;
                    h2 c2 = __float2half2_rn(c);
                    t2[0] = __hfma2(c2, x0, t2[0]);
                    t2[1] = __hfma2(c2, x1, t2[1]);
                    t2[2] = __hfma2(c2, x2, t2[2]);
                    t2[3] = __hfma2(c2, x3, t2[3]);
                    tc += c;
                }
            }
        }
        // merge dhalf pair (both halves then hold full-p t)
        #pragma unroll
        for (int k = 0; k < 4; ++k) t2[k] = __hadd2(t2[k], shflx_h2(t2[k], 32));
        tc += __shfl_xor(tc, 32);

        // ---- Phase C: ps[dd] = W·t + bcv*tc (own 8 d); butterfly over ns ----
        float ps[8];
        #pragma unroll
        for (int dd = 0; dd < 8; ++dd) {
            uint4 wv = *(const uint4*)(wbase + (size_t)dd * 8);
            h2 a = __hmul2(u2h(wv.x), t2[0]);
            a = __hfma2(u2h(wv.y), t2[1], a);
            a = __hfma2(u2h(wv.z), t2[2], a);
            a = __hfma2(u2h(wv.w), t2[3], a);
            float2 f = __half22float2(a);
            ps[dd] = f.x + f.y + bcv[dd] * tc;
        }
        #pragma unroll
        for (int mk = 1; mk < 32; mk <<= 1) {
            #pragma unroll
            for (int dd = 0; dd < 8; ++dd)
                ps[dd] += __shfl_xor(ps[dd], mk);
        }
        float ssp = 0.f;
        #pragma unroll
        for (int dd = 0; dd < 8; ++dd) ssp += ps[dd] * ps[dd];
        float ss = ssp + __shfl_xor(ssp, 32);
        float fc = sqrtf(ss) / (1.f + ss);

        if (it == ROUTE - 1) {
            if (ns == 0) {
                float* o = out + (size_t)blockIdx.x * (NOC * OD) + j * OD + dhalf * 8;
                *(float4*)o       = make_float4(ps[0]*fc, ps[1]*fc, ps[2]*fc, ps[3]*fc);
                *(float4*)(o + 4) = make_float4(ps[4]*fc, ps[5]*fc, ps[6]*fc, ps[7]*fc);
            }
            break;
        }

        // ---- Phase D: u2[k2] = sum_d v_d*W2[d,k2] (own 8 d); merge; ua += ----
        h2 u2[4];
        u2[0] = zz; u2[1] = zz; u2[2] = zz; u2[3] = zz;
        float u8 = 0.f;
        #pragma unroll
        for (int dd = 0; dd < 8; ++dd) {
            float vv = ps[dd] * fc;
            h2 v2 = __float2half2_rn(vv);
            uint4 wv = *(const uint4*)(wbase + (size_t)dd * 8);
            u2[0] = __hfma2(v2, u2h(wv.x), u2[0]);
            u2[1] = __hfma2(v2, u2h(wv.y), u2[1]);
            u2[2] = __hfma2(v2, u2h(wv.z), u2[2]);
            u2[3] = __hfma2(v2, u2h(wv.w), u2[3]);
            u8 += vv * bcv[dd];
        }
        #pragma unroll
        for (int k = 0; k < 4; ++k) u2[k] = __hadd2(u2[k], shflx_h2(u2[k], 32));
        u8 += __shfl_xor(u8, 32);
        {
            float2 f0 = __half22float2(u2[0]);
            float2 f1 = __half22float2(u2[1]);
            float2 f2 = __half22float2(u2[2]);
            float2 f3 = __half22float2(u2[3]);
            if (it == 0) {
                ua[0]=f0.x; ua[1]=f0.y; ua[2]=f1.x; ua[3]=f1.y;
                ua[4]=f2.x; ua[5]=f2.y; ua[6]=f3.x; ua[7]=f3.y; ua[8]=u8;
            } else {
                ua[0]+=f0.x; ua[1]+=f0.y; ua[2]+=f1.x; ua[3]+=f1.y;
                ua[4]+=f2.x; ua[5]+=f2.y; ua[6]+=f3.x; ua[7]+=f3.y; ua[8]+=u8;
            }
            ua2[0] = __floats2half2_rn(ua[0], ua[1]);
            ua2[1] = __floats2half2_rn(ua[2], ua[3]);
            ua2[2] = __floats2half2_rn(ua[4], ua[5]);
            ua2[3] = __floats2half2_rn(ua[6], ua[7]);
        }

        // ---- Phase E: e = exp(ua·(x,1)) for own (j, 18 p) -> LDS fp16 ----
        #pragma unroll
        for (int q = 0; q < 9; ++q) {
            #pragma unroll
            for (int s = 0; s < 2; ++s) {
                int row = (2 * (q0 + q) + s) * 32 + ns;
                uint4 xv = *(const uint4*)&xs[row * 4];
                h2 a = __hmul2(ua2[0], u2h(xv.x));
                a = __hfma2(ua2[1], u2h(xv.y), a);
                a = __hfma2(ua2[2], u2h(xv.z), a);
                a = __hfma2(ua2[3], u2h(xv.w), a);
                float2 af = __half22float2(a);
                float bb = ua[8] + af.x + af.y;
                eL[row * EROW + j] = __half_as_ushort(__float2half_rn(__expf(bb)));
            }
        }
        __syncthreads();

        // ---- Phase A': sinv[i] = 1 / sum_j e[i][j] ----
        for (int i = tid; i < NIC; i += NT) {
            const h2* er = (const h2*)&eL[i * EROW];
            h2 sA = __hadd2(__hadd2(er[0], er[1]), __hadd2(er[2], er[3]));
            sA = __hadd2(sA, er[4]);
            float2 sf = __half22float2(sA);
            *(float*)&eL[i * EROW + 10] = __frcp_rn(sf.x + sf.y);
        }
        __syncthreads();
    }
}

extern "C" void kernel_launch(void* const* d_in, const int* in_sizes, int n_in,
                              void* d_out, int out_size, void* d_ws, size_t ws_size,
                              hipStream_t stream) {
    const float* x  = (const float*)d_in[0];
    // d_in[1] = target (int32) — unused in forward
    const float* Wc = (const float*)d_in[2];
    const float* bc = (const float*)d_in[3];
    float* out = (float*)d_out;

    __half* w16 = (__half*)d_ws;        // 40960 W halfs + 5120 bias halfs = 92160 B
    convert_w<<<dim3(48), dim3(256), 0, stream>>>(Wc, bc, w16);
    caps_kernel<<<dim3(BSZ), dim3(NT), 0, stream>>>(x, w16, w16 + 40960, out);
}

// Round 10
// 100.455 us; speedup vs baseline: 1.7006x; 1.0405x over previous
//
#include <hip/hip_runtime.h>
#include <hip/hip_fp16.h>
#include <math.h>

// Capsule routing, fused, packed-fp16, register-carried exp.
// 640 thr/block: thread = (j = wave 0..9, dhalf = bit5, ns = lane&31).
// Key identity: thread (j,dhalf,ns) needs, in phase B of iter it+1, exactly
// the e = exp(ua·x) values it computed in phase E of iter it -> carry them in
// 9 h2 registers (ereg). LDS e copy (eJ) exists ONLY for A''s denominator.
// Per iter: B (c = ereg*sinv, t2 += c*x) -> C (ps = W·t, butterfly over ns)
// -> D (u = v·W, ua += u) -> E (ereg = exp(ua·x), store eJ) -> barrier ->
// A' (sinv2 = 1/sum_j eJ) -> barrier.
// Bank layouts (all free): xs 8-half rows b128; eJ lane-stride-1 h2;
// sinv2 [pr][2ns+s] f32 b64. (R9's EROW=12 stride-6 4-way conflicts removed.)
// Softmax without max-subtraction: |b| <~ 5, exp safe in f32 (validated R7).
// __launch_bounds__(640,2): allocator targets 84 VGPR (2nd arg >=5 clamps to
// 48 -> R4/R5 spill cascade; keep 2). iter-0 cs = 1.8 per half (pair-merge
// doubles to 3.6) - R8's bug.

#define BSZ   512
#define C_IN  256
#define HW    36
#define NS    32
#define NOC   10
#define OD    16
#define ROUTE 3
#define NIC   1152
#define NT    640

typedef __half2 h2;

__device__ __forceinline__ h2 u2h(unsigned int v) {
    union { unsigned int u; h2 h; } x; x.u = v; return x.h;
}
__device__ __forceinline__ h2 shflx_h2(h2 v, int m) {
    union { h2 h; int i; } x; x.h = v; x.i = __shfl_xor(x.i, m); return x.h;
}

__global__ __launch_bounds__(256) void convert_w(
    const float* __restrict__ Wc, const float* __restrict__ bc,
    __half* __restrict__ w16)   // [40960 W | 5120 bias]
{
    const int n = 40960 + 5120;
    for (int i = blockIdx.x * 256 + threadIdx.x; i < n; i += gridDim.x * 256) {
        float v = (i < 40960) ? Wc[i] : bc[i - 40960];
        w16[i] = __float2half(v);
    }
}

__global__ __launch_bounds__(NT, 2) void caps_kernel(
    const float*  __restrict__ x,     // [BSZ, 256, 36] fp32
    const __half* __restrict__ w16,   // [5120, 8] fp16
    const __half* __restrict__ bc16,  // [5120] fp16
    float* __restrict__ out)          // [BSZ, 10, 16] fp32
{
    __shared__ h2    xs[NIC * 4];          // 18432 B: row i=p*32+ns, 8 halfs
    __shared__ h2    eJ[NOC * 18 * 32];    // 23040 B: e pairs, (j*18+pr)*32+ns
    __shared__ float sinv2[NIC];           //  4608 B: 1/denom, pr*64 + ns*2 + s
    // total 46080 B -> 2 blocks/CU

    const int tid = threadIdx.x;
    const float* xb = x + (size_t)blockIdx.x * (C_IN * HW);

    // ---- Stage x -> fp16 LDS row-major (conflict-free; validated R7/R9) ----
    for (int t5 = tid; t5 < 9 * 128; t5 += NT) {
        int p4 = t5 >> 7, c2 = t5 & 127;
        int nsc = c2 >> 2, k2 = c2 & 3;
        const float* s0 = xb + (2 * c2) * HW + p4 * 4;
        float4 a = *(const float4*)s0;
        float4 b = *(const float4*)(s0 + HW);
        xs[((p4 * 4 + 0) * 32 + nsc) * 4 + k2] = __floats2half2_rn(a.x, b.x);
        xs[((p4 * 4 + 1) * 32 + nsc) * 4 + k2] = __floats2half2_rn(a.y, b.y);
        xs[((p4 * 4 + 2) * 32 + nsc) * 4 + k2] = __floats2half2_rn(a.z, b.z);
        xs[((p4 * 4 + 3) * 32 + nsc) * 4 + k2] = __floats2half2_rn(a.w, b.w);
    }
    __syncthreads();

    const int j     = tid >> 6;         // 0..9 (= wave index)
    const int dhalf = (tid >> 5) & 1;   // which 8 of the 16 out-dims
    const int ns    = tid & 31;

    const __half* wbase = w16 + (size_t)(ns * 160 + j * 16 + dhalf * 8) * 8;
    float bcv[8];
    {
        uint4 bv = *(const uint4*)(bc16 + ns * 160 + j * 16 + dhalf * 8);
        float2 b0 = __half22float2(u2h(bv.x));
        float2 b1 = __half22float2(u2h(bv.y));
        float2 b2 = __half22float2(u2h(bv.z));
        float2 b3 = __half22float2(u2h(bv.w));
        bcv[0]=b0.x; bcv[1]=b0.y; bcv[2]=b1.x; bcv[3]=b1.y;
        bcv[4]=b2.x; bcv[5]=b2.y; bcv[6]=b3.x; bcv[7]=b3.y;
    }

    const int q0 = dhalf * 9;   // own p-pairs pr = q0..q0+8
    float ua[9];                // cumulative routing coefficients (f32 canonical)
    h2    ua2[4];               // packed mirror for the fp16 dots
    h2    ereg[9];              // e = exp(b) for own (j, p-pairs), carried E->B

    for (int it = 0; it < ROUTE; ++it) {
        // ---- Phase B: t2[k2] = sum_p c*x2, tc = sum_p c (own 18 p) ----
        h2 t2[4];
        h2 zz = __float2half2_rn(0.f);
        t2[0] = zz; t2[1] = zz; t2[2] = zz; t2[3] = zz;
        float tc = 0.f;
        if (it == 0) {
            #pragma unroll
            for (int q = 0; q < 9; ++q) {
                #pragma unroll
                for (int s = 0; s < 2; ++s) {
                    int row = (2 * (q0 + q) + s) * 32 + ns;
                    uint4 xv = *(const uint4*)&xs[row * 4];
                    t2[0] = __hadd2(t2[0], u2h(xv.x));
                    t2[1] = __hadd2(t2[1], u2h(xv.y));
                    t2[2] = __hadd2(t2[2], u2h(xv.z));
                    t2[3] = __hadd2(t2[3], u2h(xv.w));
                }
            }
            h2 tenth = __float2half2_rn(0.1f);
            #pragma unroll
            for (int k = 0; k < 4; ++k) t2[k] = __hmul2(t2[k], tenth);
            tc = 1.8f;   // per-half; pair merge below doubles to 3.6 (= sum_p 0.1)
        } else {
            #pragma unroll
            for (int q = 0; q < 9; ++q) {
                int pr = q0 + q;
                float2 sv = *(const float2*)&sinv2[pr * 64 + ns * 2];
                float2 ef = __half22float2(ereg[q]);
                float c0 = ef.x * sv.x;
                float c1 = ef.y * sv.y;
                tc += c0 + c1;
                h2 c20 = __float2half2_rn(c0);
                h2 c21 = __float2half2_rn(c1);
                {
                    uint4 xv = *(const uint4*)&xs[((2 * pr + 0) * 32 + ns) * 4];
                    t2[0] = __hfma2(c20, u2h(xv.x), t2[0]);
                    t2[1] = __hfma2(c20, u2h(xv.y), t2[1]);
                    t2[2] = __hfma2(c20, u2h(xv.z), t2[2]);
                    t2[3] = __hfma2(c20, u2h(xv.w), t2[3]);
                }
                {
                    uint4 xv = *(const uint4*)&xs[((2 * pr + 1) * 32 + ns) * 4];
                    t2[0] = __hfma2(c21, u2h(xv.x), t2[0]);
                    t2[1] = __hfma2(c21, u2h(xv.y), t2[1]);
                    t2[2] = __hfma2(c21, u2h(xv.z), t2[2]);
                    t2[3] = __hfma2(c21, u2h(xv.w), t2[3]);
                }
            }
        }
        // merge dhalf pair (both halves then hold full-p t)
        #pragma unroll
        for (int k = 0; k < 4; ++k) t2[k] = __hadd2(t2[k], shflx_h2(t2[k], 32));
        tc += __shfl_xor(tc, 32);

        // ---- Phase C: ps[dd] = W·t + bcv*tc (own 8 d); butterfly over ns ----
        float ps[8];
        #pragma unroll
        for (int dd = 0; dd < 8; ++dd) {
            uint4 wv = *(const uint4*)(wbase + (size_t)dd * 8);
            h2 a = __hmul2(u2h(wv.x), t2[0]);
            a = __hfma2(u2h(wv.y), t2[1], a);
            a = __hfma2(u2h(wv.z), t2[2], a);
            a = __hfma2(u2h(wv.w), t2[3], a);
            float2 f = __half22float2(a);
            ps[dd] = f.x + f.y + bcv[dd] * tc;
        }
        #pragma unroll
        for (int mk = 1; mk < 32; mk <<= 1) {
            #pragma unroll
            for (int dd = 0; dd < 8; ++dd)
                ps[dd] += __shfl_xor(ps[dd], mk);
        }
        float ssp = 0.f;
        #pragma unroll
        for (int dd = 0; dd < 8; ++dd) ssp += ps[dd] * ps[dd];
        float ss = ssp + __shfl_xor(ssp, 32);
        float fc = sqrtf(ss) / (1.f + ss);

        if (it == ROUTE - 1) {
            if (ns == 0) {
                float* o = out + (size_t)blockIdx.x * (NOC * OD) + j * OD + dhalf * 8;
                *(float4*)o       = make_float4(ps[0]*fc, ps[1]*fc, ps[2]*fc, ps[3]*fc);
                *(float4*)(o + 4) = make_float4(ps[4]*fc, ps[5]*fc, ps[6]*fc, ps[7]*fc);
            }
            break;
        }

        // ---- Phase D: u2[k2] = sum_d v_d*W2[d,k2] (own 8 d); merge; ua += ----
        h2 u2[4];
        u2[0] = zz; u2[1] = zz; u2[2] = zz; u2[3] = zz;
        float u8 = 0.f;
        #pragma unroll
        for (int dd = 0; dd < 8; ++dd) {
            float vv = ps[dd] * fc;
            h2 v2 = __float2half2_rn(vv);
            uint4 wv = *(const uint4*)(wbase + (size_t)dd * 8);
            u2[0] = __hfma2(v2, u2h(wv.x), u2[0]);
            u2[1] = __hfma2(v2, u2h(wv.y), u2[1]);
            u2[2] = __hfma2(v2, u2h(wv.z), u2[2]);
            u2[3] = __hfma2(v2, u2h(wv.w), u2[3]);
            u8 += vv * bcv[dd];
        }
        #pragma unroll
        for (int k = 0; k < 4; ++k) u2[k] = __hadd2(u2[k], shflx_h2(u2[k], 32));
        u8 += __shfl_xor(u8, 32);
        {
            float2 f0 = __half22float2(u2[0]);
            float2 f1 = __half22float2(u2[1]);
            float2 f2 = __half22float2(u2[2]);
            float2 f3 = __half22float2(u2[3]);
            if (it == 0) {
                ua[0]=f0.x; ua[1]=f0.y; ua[2]=f1.x; ua[3]=f1.y;
                ua[4]=f2.x; ua[5]=f2.y; ua[6]=f3.x; ua[7]=f3.y; ua[8]=u8;
            } else {
                ua[0]+=f0.x; ua[1]+=f0.y; ua[2]+=f1.x; ua[3]+=f1.y;
                ua[4]+=f2.x; ua[5]+=f2.y; ua[6]+=f3.x; ua[7]+=f3.y; ua[8]+=u8;
            }
            ua2[0] = __floats2half2_rn(ua[0], ua[1]);
            ua2[1] = __floats2half2_rn(ua[2], ua[3]);
            ua2[2] = __floats2half2_rn(ua[4], ua[5]);
            ua2[3] = __floats2half2_rn(ua[6], ua[7]);
        }

        // ---- Phase E: ereg[q] = exp(ua·(x,1)) pairs; store to eJ for A' ----
        #pragma unroll
        for (int q = 0; q < 9; ++q) {
            int pr = q0 + q;
            float eb[2];
            #pragma unroll
            for (int s = 0; s < 2; ++s) {
                int row = (2 * pr + s) * 32 + ns;
                uint4 xv = *(const uint4*)&xs[row * 4];
                h2 a = __hmul2(ua2[0], u2h(xv.x));
                a = __hfma2(ua2[1], u2h(xv.y), a);
                a = __hfma2(ua2[2], u2h(xv.z), a);
                a = __hfma2(ua2[3], u2h(xv.w), a);
                float2 af = __half22float2(a);
                eb[s] = __expf(ua[8] + af.x + af.y);
            }
            ereg[q] = __floats2half2_rn(eb[0], eb[1]);
            eJ[(j * 18 + pr) * 32 + ns] = ereg[q];
        }
        __syncthreads();

        // ---- Phase A': sinv2 = 1/sum_j e  (576 pair-tasks, stride-1 banks) ----
        if (tid < 576) {
            int pr = tid >> 5, a = tid & 31;
            h2 s2 = eJ[pr * 32 + a];
            #pragma unroll
            for (int jj = 1; jj < NOC; ++jj)
                s2 = __hadd2(s2, eJ[(jj * 18 + pr) * 32 + a]);
            float2 sf = __half22float2(s2);
            *(float2*)&sinv2[pr * 64 + a * 2] =
                make_float2(__frcp_rn(sf.x), __frcp_rn(sf.y));
        }
        __syncthreads();
    }
}

extern "C" void kernel_launch(void* const* d_in, const int* in_sizes, int n_in,
                              void* d_out, int out_size, void* d_ws, size_t ws_size,
                              hipStream_t stream) {
    const float* x  = (const float*)d_in[0];
    // d_in[1] = target (int32) — unused in forward
    const float* Wc = (const float*)d_in[2];
    const float* bc = (const float*)d_in[3];
    float* out = (float*)d_out;

    __half* w16 = (__half*)d_ws;        // 40960 W halfs + 5120 bias halfs = 92160 B
    convert_w<<<dim3(48), dim3(256), 0, stream>>>(Wc, bc, w16);
    caps_kernel<<<dim3(BSZ), dim3(NT), 0, stream>>>(x, w16, w16 + 40960, out);
}